// Round 8
// baseline (286.265 us; speedup 1.0000x reference)
//
#include <hip/hip_runtime.h>
#include <hip/hip_bf16.h>

// FastUpConvolution on MI355X — round 8: 3 blocks/CU (128x64 tile) + fused
// prep launch. One implicit GEMM C[1024][16384] = W[1024][4608] *
// X[16384][4608]^T over NHWC-padded x (zero-padded taps), bf16 MFMA, f32 I/O.
//
// R7 post-mortem: ASYNC16+XOR-swizzle+per-tap W dbuf -> 165 us, MfmaUtil 41%,
// conflicts 0, WRITE ideal. Occupancy 21% (LDS 58.9 KB -> 2 blocks/CU) is the
// limiter; non-gemm overhead 105 us. R8: n-tile 64 -> W tile 8 KB, LDS 42.2 KB
// -> 3 blocks/CU at unchanged barrier cadence; zero_stats+prep_x+prep_w fused
// into one launch.
//
// ws layout:
//   x_t   : bf16 [16][34][34][512]  @ 0          (18,939,904 B)
//   W_t   : bf16 [1024 rows][9*512] @ 18,939,904 ( 9,437,184 B)  row=co*4+q
//   bias  : f32  [1024]             @ 28,377,088 (     4,096 B)  row=co*4+q
//   stats : f32  [512] sum|sumsq    @ 28,381,184 (     2,048 B)

typedef unsigned short ushort_t;
typedef __attribute__((ext_vector_type(8))) short short8;
typedef __attribute__((ext_vector_type(4))) float floatx4;
typedef __attribute__((ext_vector_type(2))) float floatx2;
typedef __attribute__((ext_vector_type(4))) unsigned short u16x4;
typedef __attribute__((ext_vector_type(8))) unsigned short u16x8;
typedef __attribute__((ext_vector_type(4))) unsigned int u32x4;

#define XT_OFF    0u
#define WT_OFF    18939904u
#define BIAS_OFF  28377088u
#define STATS_OFF 28381184u

#define NSITES 204            // 6 rows x 34 cols X footprint, 128 B per site

#define ASYNC16(g, l) __builtin_amdgcn_global_load_lds( \
    (const __attribute__((address_space(1))) void*)(g), \
    (__attribute__((address_space(3))) void*)(l), 16, 0, 0)

__device__ __forceinline__ ushort_t f2bf(float f) {
  unsigned int u = __builtin_bit_cast(unsigned int, f);
  u += 0x7fffu + ((u >> 16) & 1u);   // RNE (values finite here)
  return (ushort_t)(u >> 16);
}

// -------------------------------------------------------------- prep_all ---
// blocks 0..543: prep_x (f32 NCHW -> bf16 NHWC zero-padded x_t).
// blocks 544..1567: prep_w (W_t row=co*4+q, zero-padded taps) + bias; block
// 544 also zeros stats.
__global__ __launch_bounds__(256) void prep_all(
    const float* __restrict__ x, ushort_t* __restrict__ xt,
    const float* __restrict__ w1, const float* __restrict__ w2,
    const float* __restrict__ w3, const float* __restrict__ w4,
    const float* __restrict__ b1, const float* __restrict__ b2,
    const float* __restrict__ b3, const float* __restrict__ b4,
    ushort_t* __restrict__ wt, float* __restrict__ bias,
    float* __restrict__ stats) {
  __shared__ ushort_t lds[128 * 36];
  const int t = threadIdx.x;
  if (blockIdx.x >= 544) {            // ---- prep_w path ----
    const int nout = blockIdx.x - 544;
    if (nout == 0 && t < 256) { stats[t] = 0.f; stats[256 + t] = 0.f; }
    const int q = nout >> 8, co = nout & 255;
    const int row = co * 4 + q;
    const float* wsrc; const float* bsrc; int khl, kwl;
    if (q == 0)      { wsrc = w1; bsrc = b1; khl = 3; kwl = 3; }
    else if (q == 1) { wsrc = w2; bsrc = b2; khl = 2; kwl = 3; }
    else if (q == 2) { wsrc = w3; bsrc = b3; khl = 3; kwl = 2; }
    else             { wsrc = w4; bsrc = b4; khl = 2; kwl = 2; }
    if (t == 0) bias[row] = bsrc[co];
    ushort_t* dst = wt + (size_t)row * 4608;
    for (int tap = 0; tap < 9; ++tap) {
      const int dh = tap / 3, dw = tap % 3;
      const bool valid = (dh < khl) && (dw < kwl);
#pragma unroll
      for (int cc = 0; cc < 2; ++cc) {
        const int ci = cc * 256 + t;
        ushort_t v = 0;
        if (valid)
          v = f2bf(wsrc[(((size_t)co * 512 + ci) * khl + dh) * kwl + dw]);
        dst[tap * 512 + ci] = v;
      }
    }
    return;
  }
  // ---- prep_x path ----
  const int b = blockIdx.x;
  const int n = b / 34, hp = b % 34;
  ushort_t* dst = xt + (size_t)(n * 34 + hp) * (34 * 512);
  if (hp == 0 || hp == 33) {
    u32x4 z = {0u, 0u, 0u, 0u};
    for (int i = t; i < 2176; i += 256) ((u32x4*)dst)[i] = z;
    return;
  }
  const int h = hp - 1;
  {
    u32x4 z = {0u, 0u, 0u, 0u};
    if (t < 64) ((u32x4*)dst)[t] = z;
    else if (t < 128) ((u32x4*)(dst + 33 * 512))[t - 64] = z;
  }
  const size_t base = (size_t)n * 524288 + (size_t)h * 32;
  for (int ci0 = 0; ci0 < 512; ci0 += 128) {
    __syncthreads();
    {
      const int cil = t >> 3;
      const int w4 = (t & 7) << 2;
#pragma unroll
      for (int cc = 0; cc < 4; ++cc) {
        const int ci = cil + cc * 32;
        floatx4 v = *(const floatx4*)(x + base + (size_t)(ci0 + ci) * 1024 + w4);
        u16x4 hv;
#pragma unroll
        for (int j = 0; j < 4; ++j) hv[j] = f2bf(v[j]);
        *(u16x4*)&lds[ci * 36 + w4] = hv;
      }
    }
    __syncthreads();
    {
      const int w = t & 31;
      const int j8 = t >> 5;
#pragma unroll
      for (int cc2 = 0; cc2 < 2; ++cc2) {
        const int cil = cc2 * 64 + j8 * 8;
        u16x8 v;
#pragma unroll
        for (int j = 0; j < 8; ++j) v[j] = lds[(cil + j) * 36 + w];
        *(u16x8*)(dst + (w + 1) * 512 + ci0 + cil) = v;
      }
    }
  }
}

// ------------------------------------------------------------------ gemm ---
// Block 128 m (4h x 32w) x 64 n; 4 waves 2(m) x 2(n), 2x4 frags of
// 16x16x32 bf16. K = 8 chunks x 64 ci. Per chunk: ASYNC16-stage X footprint
// (204 sites x 128 B) + W(tap0); per tap: ASYNC16-stage W(tap+1) into the
// other 8 KB buffer, 2 k-steps x 8 MFMA, one barrier. LDS unpadded,
// XOR-swizzled (slot = c ^ (row&7)). 42.2 KB -> 3 blocks/CU.
__global__ __launch_bounds__(256) void gemm_kernel(
    const ushort_t* __restrict__ xt, const ushort_t* __restrict__ wt,
    const float* __restrict__ bias, float* __restrict__ out,
    float* __restrict__ stats) {
  __shared__ char ldsX[NSITES * 128];    // 26,112 B
  __shared__ char ldsW[2][64 * 128];     // 2 x 8,192 B
  const int tid = threadIdx.x;
  const int bx = blockIdx.x;
  const int bn = bx & 15, bm = bx >> 4;
  const int n0 = bn << 6;
  const int n_img = bm >> 3;
  const int h0p = (bm & 7) << 2;        // first padded x_t row of footprint
  const int wv = tid >> 6, lane = tid & 63;
  const int ri = lane & 15, kg = lane >> 4;
  const int wm = (wv & 1) << 6, wn = (wv >> 1) << 5;

  // ---- staging pointer precompute (XOR swizzle at issue) ----
  // X: idx = p*256+tid over 1632 = 204 sites x 8 slots; slot holds chunk
  // c = slot ^ (site&7). LDS dest = ldsX + idx*16.
  const char* xgp[7];
  char* xlp[7];
  {
    const char* xg = (const char*)(xt + (size_t)(n_img * 34 + h0p) * (34 * 512));
#pragma unroll
    for (int p = 0; p < 7; ++p) {
      const int idx = p * 256 + tid;
      const int site = idx >> 3, slot = idx & 7;
      const int c = slot ^ (site & 7);
      xgp[p] = xg + site * 1024 + (c << 4);
      xlp[p] = ldsX + idx * 16;
    }
  }
  // W: idx = p*256+tid over 512 = 64 rows x 8 slots.
  const char* wgp[2];
  char* wlp0[2];
  char* wlp1[2];
#pragma unroll
  for (int p = 0; p < 2; ++p) {
    const int idx = p * 256 + tid;
    const int row = idx >> 3, slot = idx & 7;
    const int c = slot ^ (row & 7);
    wgp[p] = (const char*)wt + (size_t)(n0 + row) * 9216 + (c << 4);
    wlp0[p] = ldsW[0] + idx * 16;
    wlp1[p] = ldsW[1] + idx * 16;
  }

  floatx4 acc[2][4] = {};

  int arow[2], bsite[4];
#pragma unroll
  for (int f = 0; f < 2; ++f) arow[f] = wn + (f << 4) + ri;
#pragma unroll
  for (int fj = 0; fj < 4; ++fj)
    bsite[fj] = ((wm >> 5) + (fj >> 1)) * 34 + ((fj & 1) << 4) + ri;

  for (int chunk = 0; chunk < 8; ++chunk) {
    const int cb = chunk << 7;
#pragma unroll
    for (int p = 0; p < 6; ++p) ASYNC16(xgp[p] + cb, xlp[p]);
    if (tid < 96) ASYNC16(xgp[6] + cb, xlp[6]);   // tail: 1632 = 6*256+96
#pragma unroll
    for (int p = 0; p < 2; ++p) ASYNC16(wgp[p] + cb, wlp0[p]);
    __syncthreads();                     // drain -> X + W(tap0) visible
#pragma unroll
    for (int tap = 0; tap < 9; ++tap) {
      if (tap < 8) {                     // prefetch W(tap+1) -> other buffer
        const int noff = ((tap + 1) << 10) + cb;
        if (tap & 1) {
#pragma unroll
          for (int p = 0; p < 2; ++p) ASYNC16(wgp[p] + noff, wlp0[p]);
        } else {
#pragma unroll
          for (int p = 0; p < 2; ++p) ASYNC16(wgp[p] + noff, wlp1[p]);
        }
      }
      const char* wb = ldsW[tap & 1];
      const int tapo = ((tap / 3) * 34 + (tap % 3)) * 128;
#pragma unroll
      for (int ks = 0; ks < 2; ++ks) {
        const int c = (ks << 2) + kg;    // 16B chunk index within row
        short8 a4[2], b4[4];
#pragma unroll
        for (int f = 0; f < 2; ++f)
          a4[f] = *(const short8*)(wb + arow[f] * 128 +
                                   ((c ^ (arow[f] & 7)) << 4));
#pragma unroll
        for (int fj = 0; fj < 4; ++fj) {
          const int srow = bsite[fj] + (tap / 3) * 34 + (tap % 3);
          b4[fj] = *(const short8*)(ldsX + bsite[fj] * 128 + tapo +
                                    ((c ^ (srow & 7)) << 4));
        }
#pragma unroll
        for (int fi = 0; fi < 2; ++fi)
#pragma unroll
          for (int fj = 0; fj < 4; ++fj)
            acc[fi][fj] = __builtin_amdgcn_mfma_f32_16x16x32_bf16(
                a4[fi], b4[fj], acc[fi][fj], 0, 0, 0);
      }
      __syncthreads();   // readers done; W(t+1) drained
    }
  }

  // ---- epilogue: +bias, dense 2x2 pixel-shuffle writes, fused BN stats ----
  // D layout: col=lane&15 (m), row=quad*4+reg (n); interleaved rows => reg=q.
  const int quad = kg, colL = ri;
#pragma unroll
  for (int fi = 0; fi < 2; ++fi) {
    const int co = ((n0 + wn + (fi << 4)) >> 2) + quad;
    const floatx4 bv = *(const floatx4*)(bias + n0 + wn + (fi << 4) + (quad << 2));
    float s = 0.f, s2 = 0.f;
    float* obase = out + ((size_t)(n_img * 256 + co) << 12);
#pragma unroll
    for (int fj = 0; fj < 4; ++fj) {
      const int mb = wm + (fj << 4) + colL;       // m within block
      const int hl = mb >> 5, w = mb & 31;
      const int h = h0p + hl;                     // global h (0..31)
      float v0 = acc[fi][fj][0] + bv[0];
      float v1 = acc[fi][fj][1] + bv[1];
      float v2 = acc[fi][fj][2] + bv[2];
      float v3 = acc[fi][fj][3] + bv[3];
      s += (v0 + v1) + (v2 + v3);
      s2 += v0 * v0 + v1 * v1 + v2 * v2 + v3 * v3;
      float* p = obase + (h << 7) + (w << 1);     // row 2h, col 2w
      floatx2 e = {v0, v2};
      floatx2 o = {v1, v3};
      *(floatx2*)p = e;
      *(floatx2*)(p + 64) = o;
    }
#pragma unroll
    for (int off = 1; off < 16; off <<= 1) {
      s += __shfl_xor(s, off);
      s2 += __shfl_xor(s2, off);
    }
    if (colL == 0) {
      atomicAdd(&stats[co], s);
      atomicAdd(&stats[256 + co], s2);
    }
  }
}

// -------------------------------------------------------------- bn_apply ---
__global__ __launch_bounds__(256) void bn_apply(
    float* __restrict__ y, const float* __restrict__ stats,
    const float* __restrict__ gamma, const float* __restrict__ beta) {
  const int b = blockIdx.x;
  const int co = b & 255;
  const int t = threadIdx.x;
  const float mean = stats[co] * (1.f / 65536.f);
  const float var = stats[256 + co] * (1.f / 65536.f) - mean * mean;
  const float rstd = rsqrtf(var + 1e-5f);
  const float scale = rstd * gamma[co];
  const float shift = beta[co] - mean * scale;
  float* p = y + (size_t)b * 4096;
#pragma unroll
  for (int it = 0; it < 4; ++it) {
    floatx4* q = (floatx4*)(p + (it * 256 + t) * 4);
    floatx4 v = *q;
#pragma unroll
    for (int e = 0; e < 4; ++e) v[e] = fmaxf(v[e] * scale + shift, 0.f);
    *q = v;
  }
}

// ---------------------------------------------------------------- launch ---
extern "C" void kernel_launch(void* const* d_in, const int* in_sizes, int n_in,
                              void* d_out, int out_size, void* d_ws,
                              size_t ws_size, hipStream_t stream) {
  const float* x  = (const float*)d_in[0];
  const float* w1 = (const float*)d_in[1];
  const float* b1 = (const float*)d_in[2];
  const float* w2 = (const float*)d_in[3];
  const float* b2 = (const float*)d_in[4];
  const float* w3 = (const float*)d_in[5];
  const float* b3 = (const float*)d_in[6];
  const float* w4 = (const float*)d_in[7];
  const float* b4 = (const float*)d_in[8];
  const float* gamma = (const float*)d_in[9];
  const float* beta  = (const float*)d_in[10];
  float* out = (float*)d_out;

  char* ws = (char*)d_ws;
  ushort_t* xt   = (ushort_t*)(ws + XT_OFF);
  ushort_t* wt   = (ushort_t*)(ws + WT_OFF);
  float*    bias = (float*)(ws + BIAS_OFF);
  float*    st   = (float*)(ws + STATS_OFF);

  prep_all<<<544 + 1024, 256, 0, stream>>>(x, xt, w1, w2, w3, w4,
                                           b1, b2, b3, b4, wt, bias, st);
  gemm_kernel<<<2048, 256, 0, stream>>>(xt, wt, bias, out, st);
  bn_apply<<<4096, 256, 0, stream>>>(out, st, gamma, beta);
}